// Round 7
// baseline (1120.163 us; speedup 1.0000x reference)
//
#include <hip/hip_runtime.h>
#include <hip/hip_cooperative_groups.h>
#include <stdint.h>

namespace cg = cooperative_groups;

// ---------------------------------------------------------------------------
// GCN 4-layer encoder. N=50000 nodes, E=1.6M edges. fp32 in/out, int32 edges.
// Round 20 -> 21:
//  * r20 post-mortem: BOTH changes failed. pullmm1 fusion = 77us vs 53us
//    separate (occupancy 24%, barrier-coupled phases serialize); 2-node
//    co-resident pull did NOT cut FETCH (121 vs 126MB) -> second-sweep
//    theory falsified. REVERTED to r19 structure (measured 308.6us).
//  * ONE COOPERATIVE MEGA-KERNEL for everything after the CSR build:
//    {prep, pullL1, mmL1, mmL2, pullL2, mmL3, pullL3, mmL4, pullL4} with
//    grid.sync() between phases. Motivation: kernel-time sum ~180us vs
//    308.6 wall -> ~130us in 10 serial launch boundaries (~12us each,
//    tail-drain+ramp of 256 CUs); r19's prep fusion already bought 13us
//    from 5 boundaries. Phase bodies are verbatim r19 device code (same
//    per-node summation order -> bitwise-identical output). Grid =
//    min(3125, occupancy*256) co-resident; launch_bounds(256,5) ~ 20
//    waves/CU = pulls' measured occupancy. Fallback to the r19 launch
//    sequence if cooperative launch is unavailable.
//  * 16-bin counting-sorted rows (r17), two-phase bucketed CSR build (r15),
//    pre-scaled pull payloads (r14), bf16 MFMA GEMMs, L1 via A(xW)=(Ax)W.
// ---------------------------------------------------------------------------

#define NN      50000
#define CAP     96           // padded in-edge slots per node; deg~Poisson(32)
#define BSZ     256          // nodes per bucket
#define NB      196          // ceil(NN/BSZ)
#define NSLICEA 256          // phase-A edge slices (== phase-B block threads)
#define CAPSEG  96           // per-(slice,bucket) segment capacity; lam~32
#define NBIN    16           // src bins (src>>12); window ~1MB of payload
#define LPAD    98           // lrow stride in ushorts (49 dwords, bank-spread)

// prep virtual-block ranges (compile-time; N fixed)
#define PREP_DINV_B   196                      // ceil(NN/256)
#define PREP_B2FS_B   6250                     // NN*128/4/256
#define PREP_WT_T     2368                     // 1024+1024+256+64 pack threads
#define PREP_WT_B     10                       // ceil(2368/256)
#define PREP_TOT_B    (PREP_DINV_B + PREP_B2FS_B + PREP_WT_B)

#define GXMM    782                            // ceil(NN/64) mm row-blocks
#define VB_P128 3125                           // ceil(NN/16)
#define VB_P64  1563                           // ceil(NN/32)
#define VB_P32  782                            // ceil(NN/64)

typedef int   iv4   __attribute__((ext_vector_type(4)));
typedef short bfv8  __attribute__((ext_vector_type(8)));   // 8 bf16 = A/B frag
typedef float fv4   __attribute__((ext_vector_type(4)));   // 4 f32  = C/D frag

__device__ __forceinline__ float bflo(uint32_t u) {  // low ushort -> fp32
    uint32_t b = u << 16; float f; __builtin_memcpy(&f, &b, 4); return f;
}
__device__ __forceinline__ float bfhi(uint32_t u) {  // high ushort -> fp32
    uint32_t b = u & 0xffff0000u; float f; __builtin_memcpy(&f, &b, 4); return f;
}
__device__ __forceinline__ unsigned short f2bf(float f) {  // RNE
    uint32_t u; __builtin_memcpy(&u, &f, 4);
    return (unsigned short)((u + 0x7fffu + ((u >> 16) & 1u)) >> 16);
}
__device__ __forceinline__ uint32_t packbf(float lo, float hi) {
    return (uint32_t)f2bf(lo) | ((uint32_t)f2bf(hi) << 16);
}

// ---- CSR build phase A: bucket edges by dst>>8 into slice-private segments.
__global__ __launch_bounds__(256) void k_bucket(uint32_t* __restrict__ seg,
                                                int* __restrict__ cnts,
                                                const int* __restrict__ src,
                                                const int* __restrict__ dst,
                                                int E) {
    __shared__ int cnt[NB];
    const int slice = blockIdx.x;
    for (int i = threadIdx.x; i < NB; i += 256) cnt[i] = 0;
    __syncthreads();
    int per = (E + NSLICEA - 1) / NSLICEA;
    per = (per + 3) & ~3;
    const int e0 = slice * per;
    uint32_t* const segp = seg + (long)slice * NB * CAPSEG;
    if (e0 < E) {
        const int e1 = (e0 + per < E) ? e0 + per : E;
        const int nv = (e1 - e0) & ~3;
        for (int t = e0 + (int)threadIdx.x * 4; t + 4 <= e0 + nv; t += 256 * 4) {
            iv4 dd = __builtin_nontemporal_load((const iv4*)(dst + t));
            iv4 ss = __builtin_nontemporal_load((const iv4*)(src + t));
#pragma unroll
            for (int q = 0; q < 4; ++q) {
                int d = dd[q];
                int b = d >> 8;
                uint32_t val = ((uint32_t)ss[q] << 8) | (uint32_t)(d & 255);
                int slot = atomicAdd(&cnt[b], 1);          // LDS atomic
                if (slot < CAPSEG) segp[b * CAPSEG + slot] = val;
            }
        }
        int tt = e0 + nv + (int)threadIdx.x;
        if (tt < e1) {
            int d = __builtin_nontemporal_load(dst + tt);
            int s = __builtin_nontemporal_load(src + tt);
            int b = d >> 8;
            uint32_t val = ((uint32_t)s << 8) | (uint32_t)(d & 255);
            int slot = atomicAdd(&cnt[b], 1);
            if (slot < CAPSEG) segp[b * CAPSEG + slot] = val;
        }
    }
    __syncthreads();
    for (int i = threadIdx.x; i < NB; i += 256)
        cnts[slice * NB + i] = (cnt[i] < CAPSEG) ? cnt[i] : CAPSEG;
}

// ---- CSR build phase B: binned drain (16 bins by src>>12) + coalesced out.
__global__ __launch_bounds__(256) void k_build(unsigned short* __restrict__ pcsr,
                                               int* __restrict__ cur,
                                               const uint32_t* __restrict__ seg,
                                               const int* __restrict__ cnts,
                                               int N) {
    __shared__ unsigned short lrow[BSZ][LPAD];   // 50.2KB
    __shared__ int bcnt[BSZ][NBIN + 1];          // 17.4KB, stride 17 dwords
    __shared__ int ldeg[BSZ];
    const int b = blockIdx.x;
    for (int i = threadIdx.x; i < BSZ * (NBIN + 1); i += 256)
        ((int*)bcnt)[i] = 0;
    __syncthreads();

    const int slice = threadIdx.x;               // 256 threads == NSLICEA
    const int n = cnts[slice * NB + b];
    const uint32_t* sp = seg + ((long)slice * NB + b) * CAPSEG;

    for (int i = 0; i < n; ++i) {                // pass 1: count
        uint32_t val = sp[i];
        atomicAdd(&bcnt[val & 255u][(val >> 8) >> 12], 1);
    }
    __syncthreads();
    {
        const int r = threadIdx.x;
        int acc = 0;
#pragma unroll
        for (int k = 0; k < NBIN; ++k) {
            int c = bcnt[r][k];
            bcnt[r][k] = acc;
            acc += c;
        }
        ldeg[r] = acc;
    }
    __syncthreads();
    for (int i = 0; i < n; ++i) {                // pass 2: binned place
        uint32_t val = sp[i];
        int d = (int)(val & 255u);
        int s = (int)(val >> 8);
        int slot = atomicAdd(&bcnt[d][s >> 12], 1);
        if (slot < CAP) lrow[d][slot] = (unsigned short)s;
    }
    __syncthreads();

    const int node0 = b * BSZ;
    int nrows = N - node0;
    if (nrows > BSZ) nrows = BSZ;
    const int total = nrows * (CAP / 2);
    for (int idx = threadIdx.x; idx < total; idx += 256) {
        int r = idx / (CAP / 2);
        int c = idx - r * (CAP / 2);
        ((uint32_t*)(pcsr + (long)(node0 + r) * CAP))[c] =
            ((const uint32_t*)lrow[r])[c];
    }
    for (int r = threadIdx.x; r < nrows; r += 256) cur[node0 + r] = ldeg[r];
}

// W[din,dout] fp32 -> Wt[din/32][dout][32] bf16 (MFMA B-operand), one elem/t
__device__ __forceinline__ void wt_pack(unsigned short* wt, const float* W,
                                        int dout, int t) {
    int kc = t / dout, n = t - kc * dout;
    unsigned short* o = wt + (long)t * 32;
#pragma unroll
    for (int kk = 0; kk < 32; ++kk) o[kk] = f2bf(W[(kc * 32 + kk) * dout + n]);
}

// ---- prep body: dinv + b2fs(x->U bf16, pre-scaled) + all 4 Wt packs.
__device__ __forceinline__ void prep_body(int b, int tid,
                                          float* dinv, const int* cur,
                                          unsigned short* U, const float* x,
                                          unsigned short* Wt1, const float* W1,
                                          unsigned short* Wt2, const float* W2,
                                          unsigned short* Wt3, const float* W3,
                                          unsigned short* Wt4, const float* W4) {
    if (b < PREP_DINV_B) {
        int t = b * 256 + tid;
        if (t < NN) dinv[t] = 1.0f / sqrtf((float)cur[t] + 1.0f);
    } else if (b < PREP_DINV_B + PREP_B2FS_B) {
        int t = (b - PREP_DINV_B) * 256 + tid;   // < NN*128/4
        float w = 1.0f / sqrtf((float)cur[t >> 5] + 1.0f);
        float4 v = reinterpret_cast<const float4*>(x)[t];
        ushort4 o;
        o.x = f2bf(v.x * w); o.y = f2bf(v.y * w);
        o.z = f2bf(v.z * w); o.w = f2bf(v.w * w);
        reinterpret_cast<ushort4*>(U)[t] = o;
    } else {
        int t = (b - PREP_DINV_B - PREP_B2FS_B) * 256 + tid;
        if (t < 1024)      wt_pack(Wt1, W1, 256, t);
        else if (t < 2048) wt_pack(Wt2, W2, 128, t - 1024);
        else if (t < 2304) wt_pack(Wt3, W3, 64, t - 2048);
        else if (t < PREP_WT_T) wt_pack(Wt4, W4, 32, t - 2304);
    }
}

// ---- pull helpers
template <int TPN>
__device__ __forceinline__ void gather4(const uint4* Hv,
                                        const unsigned short* row,
                                        int j, int f8, float* a) {
    ushort4 ii = *(const ushort4*)(row + j);
    uint4 p0 = Hv[(long)ii.x * TPN + f8];
    uint4 p1 = Hv[(long)ii.y * TPN + f8];
    uint4 p2 = Hv[(long)ii.z * TPN + f8];
    uint4 p3 = Hv[(long)ii.w * TPN + f8];
    a[0] += bflo(p0.x) + bflo(p1.x) + bflo(p2.x) + bflo(p3.x);
    a[1] += bfhi(p0.x) + bfhi(p1.x) + bfhi(p2.x) + bfhi(p3.x);
    a[2] += bflo(p0.y) + bflo(p1.y) + bflo(p2.y) + bflo(p3.y);
    a[3] += bfhi(p0.y) + bfhi(p1.y) + bfhi(p2.y) + bfhi(p3.y);
    a[4] += bflo(p0.z) + bflo(p1.z) + bflo(p2.z) + bflo(p3.z);
    a[5] += bfhi(p0.z) + bfhi(p1.z) + bfhi(p2.z) + bfhi(p3.z);
    a[6] += bflo(p0.w) + bflo(p1.w) + bflo(p2.w) + bflo(p3.w);
    a[7] += bfhi(p0.w) + bfhi(p1.w) + bfhi(p2.w) + bfhi(p3.w);
}
template <int TPN>
__device__ __forceinline__ void gather1(const uint4* Hv,
                                        const unsigned short* row,
                                        int j, int f8, float* a) {
    uint4 p = Hv[(long)row[j] * TPN + f8];
    a[0] += bflo(p.x); a[1] += bfhi(p.x);
    a[2] += bflo(p.y); a[3] += bfhi(p.y);
    a[4] += bflo(p.z); a[5] += bfhi(p.z);
    a[6] += bflo(p.w); a[7] += bfhi(p.w);
}

// ---- pull body (r19 k_pullq verbatim, blockIdx -> vb). No early return:
// out-of-range threads fall through to the phase's grid.sync().
template <int D, int BR, int OUTBF>
__device__ __forceinline__ void pull_body(int vb, int tid,
                                          void* outv,
                                          const unsigned short* Hb,
                                          const unsigned short* pcsr,
                                          const int* deg,
                                          const float* dinv,
                                          const float* bias, int n) {
    constexpr int TPN = D / 8;               // threads per node
    constexpr int NPB = 256 / TPN;           // nodes per block
    const int node = vb * NPB + tid / TPN;
    const int f8 = tid % TPN;
    if (node >= n) return;                   // inside body fn: just skips work
    const float wd = dinv[node];
    const uint4* Hv = (const uint4*)Hb;
    uint4 ps = Hv[(long)node * TPN + f8];
    float a[8];
    a[0] = bflo(ps.x); a[1] = bfhi(ps.x); a[2] = bflo(ps.y); a[3] = bfhi(ps.y);
    a[4] = bflo(ps.z); a[5] = bfhi(ps.z); a[6] = bflo(ps.w); a[7] = bfhi(ps.w);
    int dg = deg[node];
    if (dg > CAP) dg = CAP;
    const unsigned short* row = pcsr + (long)node * CAP;
    int j = 0;
    for (; j + 4 <= dg; j += 4) gather4<TPN>(Hv, row, j, f8, a);
    for (; j < dg; ++j) gather1<TPN>(Hv, row, j, f8, a);
#pragma unroll
    for (int k = 0; k < 8; ++k) a[k] *= wd;
    if (BR) {
        float4 b0 = ((const float4*)bias)[2 * f8];
        float4 b1 = ((const float4*)bias)[2 * f8 + 1];
        a[0] = fmaxf(a[0] + b0.x, 0.f); a[1] = fmaxf(a[1] + b0.y, 0.f);
        a[2] = fmaxf(a[2] + b0.z, 0.f); a[3] = fmaxf(a[3] + b0.w, 0.f);
        a[4] = fmaxf(a[4] + b1.x, 0.f); a[5] = fmaxf(a[5] + b1.y, 0.f);
        a[6] = fmaxf(a[6] + b1.z, 0.f); a[7] = fmaxf(a[7] + b1.w, 0.f);
    }
    if (OUTBF) {
        uint4 o;
        o.x = packbf(a[0], a[1]); o.y = packbf(a[2], a[3]);
        o.z = packbf(a[4], a[5]); o.w = packbf(a[6], a[7]);
        ((uint4*)outv)[(long)node * TPN + f8] = o;
    } else {
        float4 o0 = {a[0], a[1], a[2], a[3]};
        float4 o1 = {a[4], a[5], a[6], a[7]};
        ((float4*)outv)[(long)node * (D / 4) + 2 * f8] = o0;
        ((float4*)outv)[(long)node * (D / 4) + 2 * f8 + 1] = o1;
    }
}

// ---- mm body (r19 k_mm verbatim, blockIdx -> (bx,by)).
template <int DIN, int NT, int BIAS_RELU, int OUTBF, int SCALE>
__device__ __forceinline__ void mm_body(int bx, int by, int tid,
                                        const unsigned short* Xb,
                                        const unsigned short* Wt,
                                        const float* bias,
                                        const float* dinv,
                                        void* outv, int N, int dout) {
    constexpr int KI = DIN / 32;
    const int lane = tid & 63;
    const int wv   = tid >> 6;
    const int m0   = bx * 64 + wv * 16;
    const int n0   = by * (NT * 16);
    const int l15  = lane & 15;
    const int quad = lane >> 4;

    int mrow = m0 + l15;
    if (mrow >= N) mrow = N - 1;             // clamped loads; stores guarded
    const unsigned short* xp = Xb + (long)mrow * DIN + quad * 8;
    const unsigned short* wp = Wt + (long)(n0 + l15) * 32 + quad * 8;

    fv4 acc[NT];
#pragma unroll
    for (int t = 0; t < NT; ++t) acc[t] = (fv4){0.f, 0.f, 0.f, 0.f};

#pragma unroll
    for (int kc = 0; kc < KI; ++kc) {
        bfv8 a = *(const bfv8*)(xp + kc * 32);
#pragma unroll
        for (int t = 0; t < NT; ++t) {
            bfv8 b = *(const bfv8*)(wp + (long)kc * dout * 32 + t * 16 * 32);
            acc[t] = __builtin_amdgcn_mfma_f32_16x16x32_bf16(a, b, acc[t], 0, 0, 0);
        }
    }

    float sc[4];
#pragma unroll
    for (int r = 0; r < 4; ++r) {
        int m = m0 + quad * 4 + r;
        sc[r] = SCALE ? dinv[(m < N) ? m : (N - 1)] : 1.0f;
    }

#pragma unroll
    for (int t = 0; t < NT; ++t) {
        const int col = n0 + t * 16 + l15;
        float bb = BIAS_RELU ? bias[col] : 0.f;
#pragma unroll
        for (int r = 0; r < 4; ++r) {
            int m = m0 + quad * 4 + r;
            if (m < N) {
                float v = acc[t][r];
                if (BIAS_RELU) v = fmaxf(v + bb, 0.f);
                if (SCALE) v *= sc[r];
                if (OUTBF)
                    ((unsigned short*)outv)[(long)m * dout + col] = f2bf(v);
                else
                    ((float*)outv)[(long)m * dout + col] = v;
            }
        }
    }
}

// ---- THE MEGA KERNEL: prep + all 4 layers, grid.sync() between phases.
__global__ __launch_bounds__(256, 5) void k_mega(
        float* dinv, const int* cur, unsigned short* U, unsigned short* V,
        const unsigned short* pcsr, const float* x,
        unsigned short* Wt1, unsigned short* Wt2,
        unsigned short* Wt3, unsigned short* Wt4,
        const float* W1, const float* W2, const float* W3, const float* W4,
        const float* b1, const float* b2, const float* b3, const float* b4,
        float* outF, int N) {
    cg::grid_group grid = cg::this_grid();
    const int tid = threadIdx.x;
    const int nblk = gridDim.x;

    // P0: prep (dinv, x->U pre-scaled bf16, Wt packs)
    for (int b = blockIdx.x; b < PREP_TOT_B; b += nblk)
        prep_body(b, tid, dinv, cur, U, x, Wt1, W1, Wt2, W2, Wt3, W3, Wt4, W4);
    grid.sync();
    // P1: pull L1  U -> V [N,128]
    for (int vb = blockIdx.x; vb < VB_P128; vb += nblk)
        pull_body<128, 0, 1>(vb, tid, V, U, pcsr, cur, dinv, nullptr, N);
    grid.sync();
    // P2: mm L1  V @ Wt1 (+b1, relu) -> U [N,256]
    for (int vb = blockIdx.x; vb < GXMM * 4; vb += nblk)
        mm_body<128, 4, 1, 1, 0>(vb % GXMM, vb / GXMM, tid, V, Wt1, b1, dinv, U, N, 256);
    grid.sync();
    // P3: mm L2  U @ Wt2 * dinv -> V [N,128]
    for (int vb = blockIdx.x; vb < GXMM * 2; vb += nblk)
        mm_body<256, 4, 0, 1, 1>(vb % GXMM, vb / GXMM, tid, U, Wt2, nullptr, dinv, V, N, 128);
    grid.sync();
    // P4: pull L2  V -> U (+b2, relu)
    for (int vb = blockIdx.x; vb < VB_P128; vb += nblk)
        pull_body<128, 1, 1>(vb, tid, U, V, pcsr, cur, dinv, b2, N);
    grid.sync();
    // P5: mm L3  U @ Wt3 * dinv -> V [N,64]
    for (int vb = blockIdx.x; vb < GXMM; vb += nblk)
        mm_body<128, 4, 0, 1, 1>(vb, 0, tid, U, Wt3, nullptr, dinv, V, N, 64);
    grid.sync();
    // P6: pull L3  V -> U (+b3, relu)
    for (int vb = blockIdx.x; vb < VB_P64; vb += nblk)
        pull_body<64, 1, 1>(vb, tid, U, V, pcsr, cur, dinv, b3, N);
    grid.sync();
    // P7: mm L4  U @ Wt4 * dinv -> V [N,32]
    for (int vb = blockIdx.x; vb < GXMM; vb += nblk)
        mm_body<64, 2, 0, 1, 1>(vb, 0, tid, U, Wt4, nullptr, dinv, V, N, 32);
    grid.sync();
    // P8: pull L4  V -> out fp32 (+b4, relu)
    for (int vb = blockIdx.x; vb < VB_P32; vb += nblk)
        pull_body<32, 1, 0>(vb, tid, outF, V, pcsr, cur, dinv, b4, N);
}

// ---- standalone fallbacks (r19-verified) --------------------------------
__global__ __launch_bounds__(256) void k_prep(float* dinv, const int* cur,
                                              unsigned short* U, const float* x,
                                              unsigned short* Wt1, const float* W1,
                                              unsigned short* Wt2, const float* W2,
                                              unsigned short* Wt3, const float* W3,
                                              unsigned short* Wt4, const float* W4) {
    prep_body(blockIdx.x, threadIdx.x, dinv, cur, U, x, Wt1, W1, Wt2, W2, Wt3, W3, Wt4, W4);
}
template <int D, int BR, int OUTBF>
__global__ __launch_bounds__(256) void k_pullq(void* outv, const unsigned short* Hb,
                                               const unsigned short* pcsr,
                                               const int* deg, const float* dinv,
                                               const float* bias, int n) {
    pull_body<D, BR, OUTBF>(blockIdx.x, threadIdx.x, outv, Hb, pcsr, deg, dinv, bias, n);
}
template <int DIN, int NT, int BIAS_RELU, int OUTBF, int SCALE>
__global__ __launch_bounds__(256) void k_mm(const unsigned short* Xb,
                                            const unsigned short* Wt,
                                            const float* bias, const float* dinv,
                                            void* outv, int N, int dout) {
    mm_body<DIN, NT, BIAS_RELU, OUTBF, SCALE>(blockIdx.x, blockIdx.y, threadIdx.x,
                                              Xb, Wt, bias, dinv, outv, N, dout);
}

extern "C" void kernel_launch(void* const* d_in, const int* in_sizes, int n_in,
                              void* d_out, int out_size, void* d_ws, size_t ws_size,
                              hipStream_t stream) {
    const int N = NN;
    const int E = in_sizes[1] / 2;

    const float* x  = (const float*)d_in[0];
    const int* ei   = (const int*)d_in[1];
    const int* src  = ei;
    const int* dst  = ei + E;
    const float* W1 = (const float*)d_in[2];
    const float* b1 = (const float*)d_in[3];
    const float* W2 = (const float*)d_in[4];
    const float* b2 = (const float*)d_in[5];
    const float* W3 = (const float*)d_in[6];
    const float* b3 = (const float*)d_in[7];
    const float* W4 = (const float*)d_in[8];
    const float* b4 = (const float*)d_in[9];

    float* dinv = (float*)d_ws;                       // N f32
    int*   cur  = (int*)(dinv + N);                   // N i32
    unsigned short* U    = (unsigned short*)(cur + N);        // N*256 bf16
    unsigned short* V    = U + (long)N * 256;                 // N*256 bf16
    unsigned short* pcsr = V + (long)N * 256;                 // N*CAP ushort
    unsigned short* Wt1  = pcsr + (long)N * CAP;              // 128*256
    unsigned short* Wt2  = Wt1 + 128 * 256;                   // 256*128
    unsigned short* Wt3  = Wt2 + 256 * 128;                   // 128*64
    unsigned short* Wt4  = Wt3 + 128 * 64;                    // 64*32

    // CSR-build scratch: lives inside U (dead until prep overwrites it).
    uint32_t* seg  = (uint32_t*)U;
    int*      cnts = (int*)(seg + (long)NSLICEA * NB * CAPSEG);

    (void)n_in; (void)out_size; (void)ws_size;

    // ---- CSR build (2 launches)
    k_bucket<<<NSLICEA, 256, 0, stream>>>(seg, cnts, src, dst, E);
    k_build<<<NB, 256, 0, stream>>>(pcsr, cur, seg, cnts, N);

    // ---- everything else: one cooperative kernel
    static int G = 0;
    if (G == 0) {
        int nb = 0;
        if (hipOccupancyMaxActiveBlocksPerMultiprocessor(&nb, k_mega, 256, 0)
                != hipSuccess || nb < 1)
            nb = 4;
        G = nb * 256;                                  // 256 CUs on MI355X
        if (G > VB_P128) G = VB_P128;
    }
    float* outF = (float*)d_out;
    unsigned short *uU = U, *uV = V;
    const unsigned short* cpcsr = pcsr;
    int nN = N;
    void* args[] = {
        &dinv, &cur, &uU, &uV, &cpcsr, &x,
        &Wt1, &Wt2, &Wt3, &Wt4,
        &W1, &W2, &W3, &W4,
        &b1, &b2, &b3, &b4,
        &outF, &nN };
    hipError_t err = hipLaunchCooperativeKernel((const void*)k_mega,
                                                dim3(G), dim3(256), args, 0, stream);
    if (err != hipSuccess) {
        // fallback: r19-verified launch sequence
        const int GX = GXMM;
        k_prep<<<PREP_TOT_B, 256, 0, stream>>>(dinv, cur, U, x, Wt1, W1, Wt2, W2,
                                               Wt3, W3, Wt4, W4);
        k_pullq<128, 0, 1><<<VB_P128, 256, 0, stream>>>(V, U, pcsr, cur, dinv, nullptr, N);
        k_mm<128, 4, 1, 1, 0><<<dim3(GX, 4), 256, 0, stream>>>(V, Wt1, b1, dinv, U, N, 256);
        k_mm<256, 4, 0, 1, 1><<<dim3(GX, 2), 256, 0, stream>>>(U, Wt2, nullptr, dinv, V, N, 128);
        k_pullq<128, 1, 1><<<VB_P128, 256, 0, stream>>>(U, V, pcsr, cur, dinv, b2, N);
        k_mm<128, 4, 0, 1, 1><<<dim3(GX, 1), 256, 0, stream>>>(U, Wt3, nullptr, dinv, V, N, 64);
        k_pullq<64, 1, 1><<<VB_P64, 256, 0, stream>>>(U, V, pcsr, cur, dinv, b3, N);
        k_mm<64, 2, 0, 1, 1><<<dim3(GX, 1), 256, 0, stream>>>(U, Wt4, nullptr, dinv, V, N, 32);
        k_pullq<32, 1, 0><<<VB_P32, 256, 0, stream>>>(d_out, V, pcsr, cur, dinv, b4, N);
    }
}

// Round 9
// 317.997 us; speedup vs baseline: 3.5226x; 3.5226x over previous
//
#include <hip/hip_runtime.h>
#include <stdint.h>

// ---------------------------------------------------------------------------
// GCN 4-layer encoder. N=50000 nodes, E=1.6M edges. fp32 in/out, int32 edges.
// Round 22 -> 23:
//  * r22 post-mortem: FAILED on a launcher typo, not numerics — Layer-4 mm
//    writes T4' to V but the final pull read U (r19 correctly read V) ->
//    absmax 0.16. FIXED: k_pullq<32>(d_out, V, ...). The 8-edge unroll was
//    never perf-evaluated; it ships again this round unchanged.
//  * MLP theory (unchanged from r22): pull FETCH is at compulsory floor
//    (126MB = 102 payload x 8 XCDs + 9.6 pcsr + 12.8 self); lever is fill
//    RATE 3.3 -> ~4.5 TB/s. VGPR=24 proved the compiler serialized gathers
//    (16 regs alone for 4 in-flight uint4). 8-edge unroll with 8 explicit
//    uint4 temps -> MLP ~8, VGPR ~60 (still 8 waves/SIMD).
//  * 16-bin counting-sorted rows (r17), two-phase bucketed CSR build (r15),
//    pre-scaled pull payloads (r14), bf16 MFMA GEMMs, fused prep (r19).
// ---------------------------------------------------------------------------

#define NN      50000
#define CAP     96           // padded in-edge slots per node; deg~Poisson(32)
#define BSZ     256          // nodes per bucket
#define NB      196          // ceil(NN/BSZ)
#define NSLICEA 256          // phase-A edge slices (== phase-B block threads)
#define CAPSEG  96           // per-(slice,bucket) segment capacity; lam~32
#define NBIN    16           // src bins (src>>12); window ~1MB of payload
#define LPAD    98           // lrow stride in ushorts (49 dwords, bank-spread)

// k_prep block ranges (compile-time; N fixed)
#define PREP_DINV_B   196                      // ceil(NN/256)
#define PREP_B2FS_B   6250                     // NN*128/4/256
#define PREP_WT_T     2368                     // 1024+1024+256+64 pack threads
#define PREP_WT_B     10                       // ceil(2368/256)
#define PREP_TOT_B    (PREP_DINV_B + PREP_B2FS_B + PREP_WT_B)

typedef int   iv4   __attribute__((ext_vector_type(4)));
typedef short bfv8  __attribute__((ext_vector_type(8)));   // 8 bf16 = A/B frag
typedef float fv4   __attribute__((ext_vector_type(4)));   // 4 f32  = C/D frag

__device__ __forceinline__ float bflo(uint32_t u) {  // low ushort -> fp32
    uint32_t b = u << 16; float f; __builtin_memcpy(&f, &b, 4); return f;
}
__device__ __forceinline__ float bfhi(uint32_t u) {  // high ushort -> fp32
    uint32_t b = u & 0xffff0000u; float f; __builtin_memcpy(&f, &b, 4); return f;
}
__device__ __forceinline__ unsigned short f2bf(float f) {  // RNE
    uint32_t u; __builtin_memcpy(&u, &f, 4);
    return (unsigned short)((u + 0x7fffu + ((u >> 16) & 1u)) >> 16);
}
__device__ __forceinline__ uint32_t packbf(float lo, float hi) {
    return (uint32_t)f2bf(lo) | ((uint32_t)f2bf(hi) << 16);
}

// ---- CSR build phase A: bucket edges by dst>>8 into slice-private segments.
__global__ __launch_bounds__(256) void k_bucket(uint32_t* __restrict__ seg,
                                                int* __restrict__ cnts,
                                                const int* __restrict__ src,
                                                const int* __restrict__ dst,
                                                int E) {
    __shared__ int cnt[NB];
    const int slice = blockIdx.x;
    for (int i = threadIdx.x; i < NB; i += 256) cnt[i] = 0;
    __syncthreads();
    int per = (E + NSLICEA - 1) / NSLICEA;
    per = (per + 3) & ~3;
    const int e0 = slice * per;
    uint32_t* const segp = seg + (long)slice * NB * CAPSEG;
    if (e0 < E) {
        const int e1 = (e0 + per < E) ? e0 + per : E;
        const int nv = (e1 - e0) & ~3;
        for (int t = e0 + (int)threadIdx.x * 4; t + 4 <= e0 + nv; t += 256 * 4) {
            iv4 dd = __builtin_nontemporal_load((const iv4*)(dst + t));
            iv4 ss = __builtin_nontemporal_load((const iv4*)(src + t));
#pragma unroll
            for (int q = 0; q < 4; ++q) {
                int d = dd[q];
                int b = d >> 8;
                uint32_t val = ((uint32_t)ss[q] << 8) | (uint32_t)(d & 255);
                int slot = atomicAdd(&cnt[b], 1);          // LDS atomic
                if (slot < CAPSEG) segp[b * CAPSEG + slot] = val;
            }
        }
        int tt = e0 + nv + (int)threadIdx.x;
        if (tt < e1) {
            int d = __builtin_nontemporal_load(dst + tt);
            int s = __builtin_nontemporal_load(src + tt);
            int b = d >> 8;
            uint32_t val = ((uint32_t)s << 8) | (uint32_t)(d & 255);
            int slot = atomicAdd(&cnt[b], 1);
            if (slot < CAPSEG) segp[b * CAPSEG + slot] = val;
        }
    }
    __syncthreads();
    for (int i = threadIdx.x; i < NB; i += 256)
        cnts[slice * NB + i] = (cnt[i] < CAPSEG) ? cnt[i] : CAPSEG;
}

// ---- CSR build phase B: binned drain (16 bins by src>>12) + coalesced out.
__global__ __launch_bounds__(256) void k_build(unsigned short* __restrict__ pcsr,
                                               int* __restrict__ cur,
                                               const uint32_t* __restrict__ seg,
                                               const int* __restrict__ cnts,
                                               int N) {
    __shared__ unsigned short lrow[BSZ][LPAD];   // 50.2KB
    __shared__ int bcnt[BSZ][NBIN + 1];          // 17.4KB, stride 17 dwords
    __shared__ int ldeg[BSZ];
    const int b = blockIdx.x;
    for (int i = threadIdx.x; i < BSZ * (NBIN + 1); i += 256)
        ((int*)bcnt)[i] = 0;
    __syncthreads();

    const int slice = threadIdx.x;               // 256 threads == NSLICEA
    const int n = cnts[slice * NB + b];
    const uint32_t* sp = seg + ((long)slice * NB + b) * CAPSEG;

    for (int i = 0; i < n; ++i) {                // pass 1: count
        uint32_t val = sp[i];
        atomicAdd(&bcnt[val & 255u][(val >> 8) >> 12], 1);
    }
    __syncthreads();
    {
        const int r = threadIdx.x;
        int acc = 0;
#pragma unroll
        for (int k = 0; k < NBIN; ++k) {
            int c = bcnt[r][k];
            bcnt[r][k] = acc;
            acc += c;
        }
        ldeg[r] = acc;
    }
    __syncthreads();
    for (int i = 0; i < n; ++i) {                // pass 2: binned place
        uint32_t val = sp[i];
        int d = (int)(val & 255u);
        int s = (int)(val >> 8);
        int slot = atomicAdd(&bcnt[d][s >> 12], 1);
        if (slot < CAP) lrow[d][slot] = (unsigned short)s;
    }
    __syncthreads();

    const int node0 = b * BSZ;
    int nrows = N - node0;
    if (nrows > BSZ) nrows = BSZ;
    const int total = nrows * (CAP / 2);
    for (int idx = threadIdx.x; idx < total; idx += 256) {
        int r = idx / (CAP / 2);
        int c = idx - r * (CAP / 2);
        ((uint32_t*)(pcsr + (long)(node0 + r) * CAP))[c] =
            ((const uint32_t*)lrow[r])[c];
    }
    for (int r = threadIdx.x; r < nrows; r += 256) cur[node0 + r] = ldeg[r];
}

// W[din,dout] fp32 -> Wt[din/32][dout][32] bf16 (MFMA B-operand), one elem/t
__device__ __forceinline__ void wt_pack(unsigned short* __restrict__ wt,
                                        const float* __restrict__ W,
                                        int dout, int t) {
    int kc = t / dout, n = t - kc * dout;
    unsigned short* o = wt + (long)t * 32;
#pragma unroll
    for (int kk = 0; kk < 32; ++kk) o[kk] = f2bf(W[(kc * 32 + kk) * dout + n]);
}

// ---- Fused prep: dinv + b2fs(x->U bf16, pre-scaled) + all 4 Wt packs.
__global__ __launch_bounds__(256) void k_prep(float* __restrict__ dinv,
                                              const int* __restrict__ cur,
                                              unsigned short* __restrict__ U,
                                              const float* __restrict__ x,
                                              unsigned short* __restrict__ Wt1,
                                              const float* __restrict__ W1,
                                              unsigned short* __restrict__ Wt2,
                                              const float* __restrict__ W2,
                                              unsigned short* __restrict__ Wt3,
                                              const float* __restrict__ W3,
                                              unsigned short* __restrict__ Wt4,
                                              const float* __restrict__ W4) {
    const int b = blockIdx.x;
    if (b < PREP_DINV_B) {
        int t = b * 256 + threadIdx.x;
        if (t < NN) dinv[t] = 1.0f / sqrtf((float)cur[t] + 1.0f);
    } else if (b < PREP_DINV_B + PREP_B2FS_B) {
        int t = (b - PREP_DINV_B) * 256 + threadIdx.x;   // < NN*128/4
        float w = 1.0f / sqrtf((float)cur[t >> 5] + 1.0f);
        float4 v = reinterpret_cast<const float4*>(x)[t];
        ushort4 o;
        o.x = f2bf(v.x * w); o.y = f2bf(v.y * w);
        o.z = f2bf(v.z * w); o.w = f2bf(v.w * w);
        reinterpret_cast<ushort4*>(U)[t] = o;
    } else {
        int t = (b - PREP_DINV_B - PREP_B2FS_B) * 256 + threadIdx.x;
        if (t < 1024)      wt_pack(Wt1, W1, 256, t);
        else if (t < 2048) wt_pack(Wt2, W2, 128, t - 1024);
        else if (t < 2304) wt_pack(Wt3, W3, 64, t - 2048);
        else if (t < PREP_WT_T) wt_pack(Wt4, W4, 32, t - 2304);
    }
}

// Pull aggregation over PRE-SCALED bf16 payload H' (= H*dinv), fp32 accumulate:
//   out[i,:] = dinv_i * (H'[i,:] + sum_{e: dst=i} H'[src_e,:])  (+bias, relu)
// thread = (node, 8 features). 8-EDGE UNROLL: 8 uint4 gathers in flight
// before any accumulate (MLP ~8); pairwise-tree sum. Rows src-sorted.
template <int D, int BR, int OUTBF>
__global__ __launch_bounds__(256) void k_pullq(void* __restrict__ outv,
                                               const unsigned short* __restrict__ Hb,
                                               const unsigned short* __restrict__ pcsr,
                                               const int* __restrict__ deg,
                                               const float* __restrict__ dinv,
                                               const float* __restrict__ bias,
                                               int n) {
    constexpr int TPN = D / 8;               // threads per node
    constexpr int NPB = 256 / TPN;           // nodes per block
    const int node = blockIdx.x * NPB + threadIdx.x / TPN;
    const int f8 = threadIdx.x % TPN;
    if (node >= n) return;
    const float wd = dinv[node];
    const uint4* __restrict__ Hv = (const uint4*)Hb;  // 8 bf16 per uint4
    uint4 ps = Hv[(long)node * TPN + f8];             // self term, pre-scaled
    float a[8];
    a[0] = bflo(ps.x); a[1] = bfhi(ps.x); a[2] = bflo(ps.y); a[3] = bfhi(ps.y);
    a[4] = bflo(ps.z); a[5] = bfhi(ps.z); a[6] = bflo(ps.w); a[7] = bfhi(ps.w);
    int dg = deg[node];
    if (dg > CAP) dg = CAP;
    const unsigned short* __restrict__ row = pcsr + (long)node * CAP;
    int j = 0;
    for (; j + 8 <= dg; j += 8) {
        ushort4 i0 = *(const ushort4*)(row + j);
        ushort4 i1 = *(const ushort4*)(row + j + 4);
        uint4 p0 = Hv[(long)i0.x * TPN + f8];
        uint4 p1 = Hv[(long)i0.y * TPN + f8];
        uint4 p2 = Hv[(long)i0.z * TPN + f8];
        uint4 p3 = Hv[(long)i0.w * TPN + f8];
        uint4 p4 = Hv[(long)i1.x * TPN + f8];
        uint4 p5 = Hv[(long)i1.y * TPN + f8];
        uint4 p6 = Hv[(long)i1.z * TPN + f8];
        uint4 p7 = Hv[(long)i1.w * TPN + f8];
        a[0] += ((bflo(p0.x) + bflo(p1.x)) + (bflo(p2.x) + bflo(p3.x)))
              + ((bflo(p4.x) + bflo(p5.x)) + (bflo(p6.x) + bflo(p7.x)));
        a[1] += ((bfhi(p0.x) + bfhi(p1.x)) + (bfhi(p2.x) + bfhi(p3.x)))
              + ((bfhi(p4.x) + bfhi(p5.x)) + (bfhi(p6.x) + bfhi(p7.x)));
        a[2] += ((bflo(p0.y) + bflo(p1.y)) + (bflo(p2.y) + bflo(p3.y)))
              + ((bflo(p4.y) + bflo(p5.y)) + (bflo(p6.y) + bflo(p7.y)));
        a[3] += ((bfhi(p0.y) + bfhi(p1.y)) + (bfhi(p2.y) + bfhi(p3.y)))
              + ((bfhi(p4.y) + bfhi(p5.y)) + (bfhi(p6.y) + bfhi(p7.y)));
        a[4] += ((bflo(p0.z) + bflo(p1.z)) + (bflo(p2.z) + bflo(p3.z)))
              + ((bflo(p4.z) + bflo(p5.z)) + (bflo(p6.z) + bflo(p7.z)));
        a[5] += ((bfhi(p0.z) + bfhi(p1.z)) + (bfhi(p2.z) + bfhi(p3.z)))
              + ((bfhi(p4.z) + bfhi(p5.z)) + (bfhi(p6.z) + bfhi(p7.z)));
        a[6] += ((bflo(p0.w) + bflo(p1.w)) + (bflo(p2.w) + bflo(p3.w)))
              + ((bflo(p4.w) + bflo(p5.w)) + (bflo(p6.w) + bflo(p7.w)));
        a[7] += ((bfhi(p0.w) + bfhi(p1.w)) + (bfhi(p2.w) + bfhi(p3.w)))
              + ((bfhi(p4.w) + bfhi(p5.w)) + (bfhi(p6.w) + bfhi(p7.w)));
    }
    if (j + 4 <= dg) {
        ushort4 ii = *(const ushort4*)(row + j);
        uint4 p0 = Hv[(long)ii.x * TPN + f8];
        uint4 p1 = Hv[(long)ii.y * TPN + f8];
        uint4 p2 = Hv[(long)ii.z * TPN + f8];
        uint4 p3 = Hv[(long)ii.w * TPN + f8];
        a[0] += (bflo(p0.x) + bflo(p1.x)) + (bflo(p2.x) + bflo(p3.x));
        a[1] += (bfhi(p0.x) + bfhi(p1.x)) + (bfhi(p2.x) + bfhi(p3.x));
        a[2] += (bflo(p0.y) + bflo(p1.y)) + (bflo(p2.y) + bflo(p3.y));
        a[3] += (bfhi(p0.y) + bfhi(p1.y)) + (bfhi(p2.y) + bfhi(p3.y));
        a[4] += (bflo(p0.z) + bflo(p1.z)) + (bflo(p2.z) + bflo(p3.z));
        a[5] += (bfhi(p0.z) + bfhi(p1.z)) + (bfhi(p2.z) + bfhi(p3.z));
        a[6] += (bflo(p0.w) + bflo(p1.w)) + (bflo(p2.w) + bflo(p3.w));
        a[7] += (bfhi(p0.w) + bfhi(p1.w)) + (bfhi(p2.w) + bfhi(p3.w));
        j += 4;
    }
    for (; j < dg; ++j) {
        uint4 p = Hv[(long)row[j] * TPN + f8];
        a[0] += bflo(p.x); a[1] += bfhi(p.x);
        a[2] += bflo(p.y); a[3] += bfhi(p.y);
        a[4] += bflo(p.z); a[5] += bfhi(p.z);
        a[6] += bflo(p.w); a[7] += bfhi(p.w);
    }
#pragma unroll
    for (int k = 0; k < 8; ++k) a[k] *= wd;
    if (BR) {
        float4 b0 = ((const float4*)bias)[2 * f8];
        float4 b1 = ((const float4*)bias)[2 * f8 + 1];
        a[0] = fmaxf(a[0] + b0.x, 0.f); a[1] = fmaxf(a[1] + b0.y, 0.f);
        a[2] = fmaxf(a[2] + b0.z, 0.f); a[3] = fmaxf(a[3] + b0.w, 0.f);
        a[4] = fmaxf(a[4] + b1.x, 0.f); a[5] = fmaxf(a[5] + b1.y, 0.f);
        a[6] = fmaxf(a[6] + b1.z, 0.f); a[7] = fmaxf(a[7] + b1.w, 0.f);
    }
    if (OUTBF) {
        uint4 o;
        o.x = packbf(a[0], a[1]); o.y = packbf(a[2], a[3]);
        o.z = packbf(a[4], a[5]); o.w = packbf(a[6], a[7]);
        ((uint4*)outv)[(long)node * TPN + f8] = o;
    } else {
        float4 o0 = {a[0], a[1], a[2], a[3]};
        float4 o1 = {a[4], a[5], a[6], a[7]};
        ((float4*)outv)[(long)node * (D / 4) + 2 * f8] = o0;
        ((float4*)outv)[(long)node * (D / 4) + 2 * f8 + 1] = o1;
    }
}

// MFMA GEMM: out[N,dout] = Xb[N,DIN](bf16) @ W (via Wt packing), fp32 acc.
// wave = 16 rows x NT*16 cols; block = 4 waves = 64 rows. No LDS.
// SCALE: multiply output row m by dinv[m] (pre-scaling for the next pull).
template <int DIN, int NT, int BIAS_RELU, int OUTBF, int SCALE>
__global__ __launch_bounds__(256) void k_mm(const unsigned short* __restrict__ Xb,
                                            const unsigned short* __restrict__ Wt,
                                            const float* __restrict__ bias,
                                            const float* __restrict__ dinv,
                                            void* __restrict__ outv,
                                            int N, int dout) {
    constexpr int KI = DIN / 32;
    const int lane = threadIdx.x & 63;
    const int wv   = threadIdx.x >> 6;
    const int m0   = blockIdx.x * 64 + wv * 16;
    const int n0   = blockIdx.y * (NT * 16);
    const int l15  = lane & 15;
    const int quad = lane >> 4;

    int mrow = m0 + l15;
    if (mrow >= N) mrow = N - 1;                     // clamped loads; stores guarded
    const unsigned short* xp = Xb + (long)mrow * DIN + quad * 8;
    const unsigned short* wp = Wt + (long)(n0 + l15) * 32 + quad * 8;

    fv4 acc[NT];
#pragma unroll
    for (int t = 0; t < NT; ++t) acc[t] = (fv4){0.f, 0.f, 0.f, 0.f};

#pragma unroll
    for (int kc = 0; kc < KI; ++kc) {
        bfv8 a = *(const bfv8*)(xp + kc * 32);
#pragma unroll
        for (int t = 0; t < NT; ++t) {
            bfv8 b = *(const bfv8*)(wp + (long)kc * dout * 32 + t * 16 * 32);
            acc[t] = __builtin_amdgcn_mfma_f32_16x16x32_bf16(a, b, acc[t], 0, 0, 0);
        }
    }

    float sc[4];
#pragma unroll
    for (int r = 0; r < 4; ++r) {
        int m = m0 + quad * 4 + r;
        sc[r] = SCALE ? dinv[(m < N) ? m : (N - 1)] : 1.0f;
    }

#pragma unroll
    for (int t = 0; t < NT; ++t) {
        const int col = n0 + t * 16 + l15;
        float bb = BIAS_RELU ? bias[col] : 0.f;
#pragma unroll
        for (int r = 0; r < 4; ++r) {
            int m = m0 + quad * 4 + r;
            if (m < N) {
                float v = acc[t][r];
                if (BIAS_RELU) v = fmaxf(v + bb, 0.f);
                if (SCALE) v *= sc[r];
                if (OUTBF)
                    ((unsigned short*)outv)[(long)m * dout + col] = f2bf(v);
                else
                    ((float*)outv)[(long)m * dout + col] = v;
            }
        }
    }
}

extern "C" void kernel_launch(void* const* d_in, const int* in_sizes, int n_in,
                              void* d_out, int out_size, void* d_ws, size_t ws_size,
                              hipStream_t stream) {
    const int N = NN;
    const int E = in_sizes[1] / 2;

    const float* x  = (const float*)d_in[0];
    const int* ei   = (const int*)d_in[1];
    const int* src  = ei;
    const int* dst  = ei + E;
    const float* W1 = (const float*)d_in[2];
    const float* b1 = (const float*)d_in[3];
    const float* W2 = (const float*)d_in[4];
    const float* b2 = (const float*)d_in[5];
    const float* W3 = (const float*)d_in[6];
    const float* b3 = (const float*)d_in[7];
    const float* W4 = (const float*)d_in[8];
    const float* b4 = (const float*)d_in[9];

    float* dinv = (float*)d_ws;                       // N f32
    int*   cur  = (int*)(dinv + N);                   // N i32
    unsigned short* U    = (unsigned short*)(cur + N);        // N*256 bf16
    unsigned short* V    = U + (long)N * 256;                 // N*256 bf16
    unsigned short* pcsr = V + (long)N * 256;                 // N*CAP ushort
    unsigned short* Wt1  = pcsr + (long)N * CAP;              // 128*256
    unsigned short* Wt2  = Wt1 + 128 * 256;                   // 256*128
    unsigned short* Wt3  = Wt2 + 256 * 128;                   // 128*64
    unsigned short* Wt4  = Wt3 + 128 * 64;                    // 64*32

    // CSR-build scratch: lives inside U (dead until k_prep overwrites it).
    uint32_t* seg  = (uint32_t*)U;
    int*      cnts = (int*)(seg + (long)NSLICEA * NB * CAPSEG);

    (void)n_in; (void)out_size; (void)ws_size;

    const int GX = (N + 63) / 64;                     // 782 row-blocks

    // ---- CSR build (2-phase bucketed, binned rows) + fused prep
    k_bucket<<<NSLICEA, 256, 0, stream>>>(seg, cnts, src, dst, E);
    k_build<<<NB, 256, 0, stream>>>(pcsr, cur, seg, cnts, N);
    k_prep<<<PREP_TOT_B, 256, 0, stream>>>(
        dinv, cur, U, x, Wt1, W1, Wt2, W2, Wt3, W3, Wt4, W4);

    // ---- Layer 1: P0b = Prop(x') [N,128] -> V; H1b = relu(P0b@W1+b1) [N,256] -> U
    k_pullq<128, 0, 1><<<(N + 15) / 16, 256, 0, stream>>>(V, U, pcsr, cur, dinv, nullptr, N);
    k_mm<128, 4, 1, 1, 0><<<dim3(GX, 4), 256, 0, stream>>>(V, Wt1, b1, dinv, U, N, 256);

    // ---- Layer 2: T2' = (H1b@W2)*dinv [N,128] -> V; H2b = relu(Prop+b2) -> U
    k_mm<256, 4, 0, 1, 1><<<dim3(GX, 2), 256, 0, stream>>>(U, Wt2, nullptr, dinv, V, N, 128);
    k_pullq<128, 1, 1><<<(N + 15) / 16, 256, 0, stream>>>(U, V, pcsr, cur, dinv, b2, N);

    // ---- Layer 3: T3' = (H2b@W3)*dinv [N,64] -> V; H3b = relu(Prop+b3) -> U
    k_mm<128, 4, 0, 1, 1><<<dim3(GX, 1), 256, 0, stream>>>(U, Wt3, nullptr, dinv, V, N, 64);
    k_pullq<64, 1, 1><<<(N + 31) / 32, 256, 0, stream>>>(U, V, pcsr, cur, dinv, b3, N);

    // ---- Layer 4: T4' = (H3b@W4)*dinv [N,32] -> V; out = relu(Prop+b4) fp32
    k_mm<64, 2, 0, 1, 1><<<dim3(GX, 1), 256, 0, stream>>>(U, Wt4, nullptr, dinv, V, N, 32);
    k_pullq<32, 1, 0><<<(N + 63) / 64, 256, 0, stream>>>(d_out, V, pcsr, cur, dinv, b4, N);
}